// Round 17
// baseline (199.171 us; speedup 1.0000x reference)
//
#include <hip/hip_runtime.h>

#define H_ 256
#define W_ 256
#define HW_ (H_*W_)

typedef __attribute__((ext_vector_type(8))) short bf16x8;
typedef __attribute__((ext_vector_type(4))) float f32x4;

// ---- bf16 helpers ----------------------------------------------------------
__device__ __forceinline__ float bflo(unsigned u) { return __builtin_bit_cast(float, u << 16); }
__device__ __forceinline__ float bfhi(unsigned u) { return __builtin_bit_cast(float, u & 0xffff0000u); }
__device__ __forceinline__ unsigned f2bf(float f) {
    unsigned b = __builtin_bit_cast(unsigned, f);
    b += 0x7fffu + ((b >> 16) & 1u);
    return b >> 16;
}
__device__ __forceinline__ unsigned cvtpk(float lo, float hi) {
    unsigned r;
    asm("v_cvt_pk_bf16_f32 %0, %1, %2" : "=v"(r) : "v"(lo), "v"(hi));
    return r;
}
__device__ __forceinline__ void unpack8(uint4 v, float* f) {
    f[0] = bflo(v.x); f[1] = bfhi(v.x); f[2] = bflo(v.y); f[3] = bfhi(v.y);
    f[4] = bflo(v.z); f[5] = bfhi(v.z); f[6] = bflo(v.w); f[7] = bfhi(v.w);
}

// ---------------------------------------------------------------------------
// prep: all weights -> bf16 [k][o][c] tiles.
// ---------------------------------------------------------------------------
__global__ void prep_weights(const float* __restrict__ wdef, unsigned short* __restrict__ wdefb,
                             const float* __restrict__ wdc, unsigned short* __restrict__ wdcb,
                             const float* __restrict__ woff, unsigned short* __restrict__ woffb) {
    int idx = blockIdx.x * 256 + threadIdx.x;   // grid covers 36864
    if (idx < 36864) {
        int k = idx >> 12, o = (idx >> 6) & 63, c = idx & 63;
        wdefb[idx] = (unsigned short)f2bf(wdef[(o * 64 + c) * 9 + k]);
        wdcb[idx]  = (unsigned short)f2bf(wdc[(c * 64 + o) * 9 + (8 - k)]);
    }
    if (idx < 18432) {
        int k = idx >> 11, o = (idx >> 6) & 31, c = idx & 63;
        woffb[idx] = (o < 18) ? (unsigned short)f2bf(woff[(o * 64 + c) * 9 + k])
                              : (unsigned short)0;
    }
}

// ---------------------------------------------------------------------------
// x NCHW f32 -> xb NHWC bf16 (LDS transpose, 64px x 64c tiles)
// ---------------------------------------------------------------------------
__global__ __launch_bounds__(256) void x_to_nhwc(const float* __restrict__ x,
                                                 unsigned short* __restrict__ xb) {
    __shared__ unsigned short t[64 * 72];
    int tid = threadIdx.x;
    int b = blockIdx.x >> 10;
    long pxb = (long)(blockIdx.x & 1023) * 64;
    const float* xp = x + (long)b * 64 * HW_ + pxb;
    int px = tid & 63, cg = tid >> 6;
    for (int c = cg; c < 64; c += 4)
        t[px * 72 + c] = (unsigned short)f2bf(xp[(long)c * HW_ + px]);
    __syncthreads();
    int spx = tid >> 2, q = tid & 3;
    unsigned short* dst = xb + ((long)b * HW_ + pxb + spx) * 64 + q * 16;
    *(uint4*)dst       = *(const uint4*)&t[spx * 72 + q * 16];
    *(uint4*)(dst + 8) = *(const uint4*)&t[spx * 72 + q * 16 + 8];
}

// ---------------------------------------------------------------------------
// conv1 via MFMA, double-buffered pipelined staging (r13-exact).
// xb NHWC bf16 -> h NHWC bf16 (+bias+relu). Block 128px x 64o, 4 waves.
// ---------------------------------------------------------------------------
__global__ __launch_bounds__(256, 4) void conv1_mfma(const unsigned short* __restrict__ xb,
                                                     const unsigned short* __restrict__ wdcb,
                                                     const float* __restrict__ bias,
                                                     unsigned short* __restrict__ h) {
    __shared__ __align__(16) unsigned short sA[2][130 * 72];   // 37.4KB

    int tid = threadIdx.x;
    int linear = (blockIdx.x & 7) * 128 + (blockIdx.x >> 3);   // XCD swizzle, 1024 blocks
    int bx = linear & 1;
    int y  = (linear >> 1) & 255;
    int b  = linear >> 9;
    int X0 = bx * 128;

    int wave = tid >> 6, lane = tid & 63;
    int lr = lane & 15, lg = lane >> 4;
    int n0 = wave * 16;

    f32x4 acc[8];
#pragma unroll
    for (int m = 0; m < 8; ++m) { acc[m][0]=0.f; acc[m][1]=0.f; acc[m][2]=0.f; acc[m][3]=0.f; }

    const unsigned short* xbb = xb + (long)b * HW_ * 64;
    const unsigned short* pb  = wdcb + (n0 + lr) * 64 + lg * 8;

    int r0 = (y == 0) ? 1 : 0;
    int r1 = (y == H_ - 1) ? 1 : 2;

    uint4 L[5];
    auto LOADROW = [&](int yr) {
        const unsigned short* src = xbb + (long)yr * (W_ * 64);
#pragma unroll
        for (int t = 0; t < 5; ++t) {
            int e = tid + t * 256;
            uint4 v = { 0u, 0u, 0u, 0u };
            if (e < 1040) {
                int col = X0 - 1 + (e >> 3);
                if (col >= 0 && col < W_)
                    v = *(const uint4*)&src[(long)col * 64 + (e & 7) * 8];
            }
            L[t] = v;
        }
    };

    LOADROW(y + r0 - 1);
    int pa = 0;
    for (int ky = r0; ky <= r1; ++ky, ++pa) {
        unsigned short* buf = sA[pa & 1];
#pragma unroll
        for (int t = 0; t < 5; ++t) {           // ds_write staged regs
            int e = tid + t * 256;
            if (e < 1040) *(uint4*)&buf[(e >> 3) * 72 + (e & 7) * 8] = L[t];
        }
        if (ky < r1) LOADROW(y + ky);           // next row flies over MFMA
        asm volatile("s_waitcnt lgkmcnt(0)" ::: "memory");
        __builtin_amdgcn_s_barrier();
        asm volatile("" ::: "memory");
#pragma unroll
        for (int kx = 0; kx < 3; ++kx) {
            int k = ky * 3 + kx;
            bf16x8 b0 = *(const bf16x8*)(pb + k * 4096);
            bf16x8 b1 = *(const bf16x8*)(pb + k * 4096 + 32);
#pragma unroll
            for (int m = 0; m < 8; ++m) {
                const unsigned short* ap = &buf[(m * 16 + lr + kx) * 72 + lg * 8];
                bf16x8 a0 = *(const bf16x8*)ap;
                bf16x8 a1 = *(const bf16x8*)(ap + 32);
                acc[m] = __builtin_amdgcn_mfma_f32_16x16x32_bf16(a0, b0, acc[m], 0, 0, 0);
                acc[m] = __builtin_amdgcn_mfma_f32_16x16x32_bf16(a1, b1, acc[m], 0, 0, 0);
            }
        }
    }

    // epilogue: bias+relu, repack via LDS (sA[0]) to NHWC bf16
    __syncthreads();
    float bv = bias[n0 + lr];
    unsigned short* cs = sA[0];
#pragma unroll
    for (int m = 0; m < 8; ++m)
#pragma unroll
        for (int r = 0; r < 4; ++r) {
            float vv = fmaxf(acc[m][r] + bv, 0.f);
            cs[(m * 16 + lg * 4 + r) * 72 + n0 + lr] = (unsigned short)f2bf(vv);
        }
    __syncthreads();
    int spx = tid >> 1, sc0 = (tid & 1) * 32;
    unsigned short* dst = h + ((long)b * HW_ + (long)y * W_ + X0 + spx) * 64 + sc0;
    const unsigned short* srcp = &cs[spx * 72 + sc0];
#pragma unroll
    for (int q = 0; q < 4; ++q)
        *(uint4*)(dst + q * 8) = *(const uint4*)(srcp + q * 8);
}

// ---------------------------------------------------------------------------
// conv2 via MFMA, double-buffered pipelined staging, N=18 padded to 32
// (r13-exact). h NHWC bf16 -> off NCHW f32. Block 128px x 32o, 4 waves.
// ---------------------------------------------------------------------------
__global__ __launch_bounds__(256, 4) void conv2_mfma(const unsigned short* __restrict__ h,
                                                     const unsigned short* __restrict__ woffb,
                                                     const float* __restrict__ bias,
                                                     float* __restrict__ off) {
    __shared__ __align__(16) unsigned short sA[2][130 * 72];

    int tid = threadIdx.x;
    int linear = (blockIdx.x & 7) * 128 + (blockIdx.x >> 3);   // 1024 blocks
    int bx = linear & 1;
    int y  = (linear >> 1) & 255;
    int b  = linear >> 9;
    int X0 = bx * 128;

    int wave = tid >> 6, lane = tid & 63;
    int lr = lane & 15, lg = lane >> 4;
    int pxh = wave & 1, nh = wave >> 1;
    int n0 = nh * 16;
    int pxb = pxh * 64;

    f32x4 acc[4];
#pragma unroll
    for (int m = 0; m < 4; ++m) { acc[m][0]=0.f; acc[m][1]=0.f; acc[m][2]=0.f; acc[m][3]=0.f; }

    const unsigned short* hb = h + (long)b * HW_ * 64;
    const unsigned short* pb = woffb + (n0 + lr) * 64 + lg * 8;

    int r0 = (y == 0) ? 1 : 0;
    int r1 = (y == H_ - 1) ? 1 : 2;

    uint4 L[5];
    auto LOADROW = [&](int yr) {
        const unsigned short* src = hb + (long)yr * (W_ * 64);
#pragma unroll
        for (int t = 0; t < 5; ++t) {
            int e = tid + t * 256;
            uint4 v = { 0u, 0u, 0u, 0u };
            if (e < 1040) {
                int col = X0 - 1 + (e >> 3);
                if (col >= 0 && col < W_)
                    v = *(const uint4*)&src[(long)col * 64 + (e & 7) * 8];
            }
            L[t] = v;
        }
    };

    LOADROW(y + r0 - 1);
    int pa = 0;
    for (int ky = r0; ky <= r1; ++ky, ++pa) {
        unsigned short* buf = sA[pa & 1];
#pragma unroll
        for (int t = 0; t < 5; ++t) {
            int e = tid + t * 256;
            if (e < 1040) *(uint4*)&buf[(e >> 3) * 72 + (e & 7) * 8] = L[t];
        }
        if (ky < r1) LOADROW(y + ky);
        asm volatile("s_waitcnt lgkmcnt(0)" ::: "memory");
        __builtin_amdgcn_s_barrier();
        asm volatile("" ::: "memory");
#pragma unroll
        for (int kx = 0; kx < 3; ++kx) {
            int k = ky * 3 + kx;
            bf16x8 b0 = *(const bf16x8*)(pb + k * 2048);
            bf16x8 b1 = *(const bf16x8*)(pb + k * 2048 + 32);
#pragma unroll
            for (int m = 0; m < 4; ++m) {
                const unsigned short* ap = &buf[(pxb + m * 16 + lr + kx) * 72 + lg * 8];
                bf16x8 a0 = *(const bf16x8*)ap;
                bf16x8 a1 = *(const bf16x8*)(ap + 32);
                acc[m] = __builtin_amdgcn_mfma_f32_16x16x32_bf16(a0, b0, acc[m], 0, 0, 0);
                acc[m] = __builtin_amdgcn_mfma_f32_16x16x32_bf16(a1, b1, acc[m], 0, 0, 0);
            }
        }
    }

    int o = n0 + lr;
    if (o < 18) {
        float bv = bias[o];
        float* op = off + ((long)b * 18 + o) * HW_ + (long)y * W_ + X0 + pxb;
#pragma unroll
        for (int m = 0; m < 4; ++m) {
            float4 r = { acc[m][0] + bv, acc[m][1] + bv, acc[m][2] + bv, acc[m][3] + bv };
            *(float4*)(op + m * 16 + lg * 4) = r;
        }
    }
}

// ---------------------------------------------------------------------------
// deform conv via MFMA — r16 winner (49.7 µs) with occupancy raised 5 -> 8
// blocks/CU: measured live set 48 VGPR < 64 cap (headroom 16), LDS 8x16KB =
// 128KB < 160KB. No gather prefetch (TLP covers exposed latency); offsets +
// weights prefetched; swizzled val LDS; lgkm-only barrier per tap.
// ---------------------------------------------------------------------------
struct Pass16 {
    uint4 a00, a01, a10, a11;   // corners, chans c0..c0+8
    uint4 b00, b01, b10, b11;   // corners, chans c0+8..c0+16
    float w00, w01, w10, w11;
};

__device__ __forceinline__ Pass16 issue16(const unsigned short* __restrict__ hb,
                                          int k, int y, int px, float dy, float dx, int c0) {
    Pass16 s;
    float py  = (float)(y - 1 + k / 3) + dy;
    float pxs = (float)(px - 1 + k % 3) + dx;
    float y0f = floorf(py), x0f = floorf(pxs);
    int iy0 = (int)y0f, ix0 = (int)x0f;
    float wy1 = py - y0f, wx1 = pxs - x0f;
    float wy0 = 1.f - wy1, wx0 = 1.f - wx1;
    bool vy0 = (iy0 >= 0) && (iy0 < H_);
    bool vy1 = (iy0 >= -1) && (iy0 < H_ - 1);
    bool vx0 = (ix0 >= 0) && (ix0 < W_);
    bool vx1 = (ix0 >= -1) && (ix0 < W_ - 1);
    int cy0 = min(max(iy0, 0), H_ - 1), cy1 = min(max(iy0 + 1, 0), H_ - 1);
    int cx0 = min(max(ix0, 0), W_ - 1), cx1 = min(max(ix0 + 1, 0), W_ - 1);
    s.w00 = wy0 * wx0 * ((vy0 && vx0) ? 1.f : 0.f);
    s.w01 = wy0 * wx1 * ((vy0 && vx1) ? 1.f : 0.f);
    s.w10 = wy1 * wx0 * ((vy1 && vx0) ? 1.f : 0.f);
    s.w11 = wy1 * wx1 * ((vy1 && vx1) ? 1.f : 0.f);
    int r00 = (cy0 * W_ + cx0) * 64 + c0, r01 = (cy0 * W_ + cx1) * 64 + c0;
    int r10 = (cy1 * W_ + cx0) * 64 + c0, r11 = (cy1 * W_ + cx1) * 64 + c0;
    s.a00 = *(const uint4*)&hb[r00];     s.a01 = *(const uint4*)&hb[r01];
    s.a10 = *(const uint4*)&hb[r10];     s.a11 = *(const uint4*)&hb[r11];
    s.b00 = *(const uint4*)&hb[r00 + 8]; s.b01 = *(const uint4*)&hb[r01 + 8];
    s.b10 = *(const uint4*)&hb[r10 + 8]; s.b11 = *(const uint4*)&hb[r11 + 8];
    return s;
}

__device__ __forceinline__ uint4 interp8u(uint4 q0, uint4 q1, uint4 q2, uint4 q3,
                                          float w00, float w01, float w10, float w11) {
    float g0[8], g1[8], g2[8], g3[8];
    unpack8(q0, g0); unpack8(q1, g1); unpack8(q2, g2); unpack8(q3, g3);
    unsigned r[4];
#pragma unroll
    for (int j = 0; j < 4; ++j) {
        float lo = fmaf(g3[2*j],   w11, fmaf(g2[2*j],   w10, fmaf(g1[2*j],   w01, g0[2*j]   * w00)));
        float hi = fmaf(g3[2*j+1], w11, fmaf(g2[2*j+1], w10, fmaf(g1[2*j+1], w01, g0[2*j+1] * w00)));
        r[j] = cvtpk(lo, hi);
    }
    uint4 u = { r[0], r[1], r[2], r[3] };
    return u;
}

__global__ __launch_bounds__(256, 8) void deform_mfma(const unsigned short* __restrict__ h,
                                                      const float* __restrict__ off,
                                                      const unsigned short* __restrict__ wdefb,
                                                      const float* __restrict__ bias,
                                                      float* __restrict__ out) {
    __shared__ __align__(16) unsigned short val[2][64 * 64];   // 16KB double buffer

    int tid = threadIdx.x;
    int linear = (blockIdx.x & 7) * 256 + (blockIdx.x >> 3);   // 2048 blocks, XCD swizzle
    int b  = linear >> 10;
    int y  = (linear >> 2) & 255;
    int x0 = (linear & 3) * 64;

    int lane = tid & 63, wave = tid >> 6;
    int lr = lane & 15, lg = lane >> 4;
    int n0 = wave * 16;
    int gpx = tid >> 2;            // gather px 0..63 (channel-major: 4 lanes/pixel)
    int gc  = tid & 3;             // 16-chan chunk
    int c0  = gc * 16;
    int gx  = x0 + gpx;

    f32x4 acc[4];
#pragma unroll
    for (int m = 0; m < 4; ++m) { acc[m][0]=0.f; acc[m][1]=0.f; acc[m][2]=0.f; acc[m][3]=0.f; }

    const unsigned short* hb   = h + (long)b * HW_ * 64;
    const float* ofb  = off + (long)b * 18 * HW_ + y * W_ + gx;
    const unsigned short* bsrc = wdefb + (n0 + lr) * 64 + lg * 8;

    // prologue: tap-0 offsets
    float dyc = ofb[0], dxc = ofb[HW_];

    // swizzled LDS slots (shorts): slot index 0..7 within a 128B px row
    int slotL = ((2 * gc)     ^ (gpx & 7)) * 8;
    int slotH = ((2 * gc + 1) ^ (gpx & 7)) * 8;
    int rdL   = ((lg)     ^ (lr & 7)) * 8;
    int rdH   = ((lg + 4) ^ (lr & 7)) * 8;

    for (int k = 0; k < 9; ++k) {
        // weights for tap k + offsets for tap k+1 (issued before gathers)
        bf16x8 bc0 = *(const bf16x8*)(bsrc + k * 4096);
        bf16x8 bc1 = *(const bf16x8*)(bsrc + k * 4096 + 32);
        float dyn = 0.f, dxn = 0.f;
        if (k < 8) { dyn = ofb[(2 * k + 2) * HW_]; dxn = ofb[(2 * k + 3) * HW_]; }

        // gathers for tap k — waited immediately by interp (exposed latency,
        // covered by 8 blocks/CU TLP)
        Pass16 S = issue16(hb, k, y, gx, dyc, dxc, c0);

        unsigned short* vb = val[k & 1];
        *(uint4*)&vb[gpx * 64 + slotL] = interp8u(S.a00, S.a01, S.a10, S.a11,
                                                  S.w00, S.w01, S.w10, S.w11);
        *(uint4*)&vb[gpx * 64 + slotH] = interp8u(S.b00, S.b01, S.b10, S.b11,
                                                  S.w00, S.w01, S.w10, S.w11);

        asm volatile("s_waitcnt lgkmcnt(0)" ::: "memory");  // my ds_writes committed
        __builtin_amdgcn_s_barrier();                       // vmcnt NOT drained
        asm volatile("" ::: "memory");                      // keep ds_reads below barrier

        __builtin_amdgcn_s_setprio(1);
#pragma unroll
        for (int m = 0; m < 4; ++m) {
            const unsigned short* ap = &vb[(m * 16 + lr) * 64];
            bf16x8 a0 = *(const bf16x8*)&ap[rdL];
            bf16x8 a1 = *(const bf16x8*)&ap[rdH];
            acc[m] = __builtin_amdgcn_mfma_f32_16x16x32_bf16(a0, bc0, acc[m], 0, 0, 0);
            acc[m] = __builtin_amdgcn_mfma_f32_16x16x32_bf16(a1, bc1, acc[m], 0, 0, 0);
        }
        __builtin_amdgcn_s_setprio(0);

        dyc = dyn; dxc = dxn;
    }

    // epilogue: D col=lane&15 -> o = n0+lr; row -> px = m*16+lg*4+r
    float bv = bias[n0 + lr];
    float* outb = out + ((long)b * 64 + n0 + lr) * HW_ + y * W_ + x0;
#pragma unroll
    for (int m = 0; m < 4; ++m) {
        float4 r = { fmaxf(acc[m][0] + bv, 0.f), fmaxf(acc[m][1] + bv, 0.f),
                     fmaxf(acc[m][2] + bv, 0.f), fmaxf(acc[m][3] + bv, 0.f) };
        *(float4*)(outb + m * 16 + lg * 4) = r;
    }
}

// ---------------------------------------------------------------------------
extern "C" void kernel_launch(void* const* d_in, const int* in_sizes, int n_in,
                              void* d_out, int out_size, void* d_ws, size_t ws_size,
                              hipStream_t stream) {
    const float* x        = (const float*)d_in[0];
    const float* w_deconv = (const float*)d_in[1];
    const float* b_deconv = (const float*)d_in[2];
    const float* w_off    = (const float*)d_in[3];
    const float* b_off    = (const float*)d_in[4];
    const float* w_def    = (const float*)d_in[5];
    const float* b_def    = (const float*)d_in[6];
    float* out = (float*)d_out;

    char* ws = (char*)d_ws;
    unsigned short* xbb   = (unsigned short*)ws;               // 16,777,216 B
    unsigned short* hbf   = (unsigned short*)(ws + 16777216);  // 16,777,216 B
    float* offset         = (float*)(ws + 33554432);           //  9,437,184 B
    unsigned short* wdcb  = (unsigned short*)(ws + 42991616);  //     73,728 B
    unsigned short* wdefb = (unsigned short*)(ws + 43065344);  //     73,728 B
    unsigned short* woffb = (unsigned short*)(ws + 43139072);  //     36,864 B

    prep_weights<<<144, 256, 0, stream>>>(w_def, wdefb, w_deconv, wdcb, w_off, woffb);
    x_to_nhwc<<<2048, 256, 0, stream>>>(x, xbb);
    conv1_mfma<<<1024, 256, 0, stream>>>(xbb, wdcb, b_deconv, hbf);
    conv2_mfma<<<1024, 256, 0, stream>>>(hbf, woffb, b_off, offset);
    deform_mfma<<<2048, 256, 0, stream>>>(hbf, offset, wdefb, b_def, out);
}

// Round 18
// 97.216 us; speedup vs baseline: 2.0487x; 2.0487x over previous
//
#include <hip/hip_runtime.h>

#define H_ 256
#define W_ 256
#define HW_ (H_*W_)

typedef __attribute__((ext_vector_type(8))) short bf16x8;
typedef __attribute__((ext_vector_type(4))) float f32x4;

// ---- bf16 helpers ----------------------------------------------------------
__device__ __forceinline__ float bflo(unsigned u) { return __builtin_bit_cast(float, u << 16); }
__device__ __forceinline__ float bfhi(unsigned u) { return __builtin_bit_cast(float, u & 0xffff0000u); }
__device__ __forceinline__ unsigned f2bf(float f) {
    unsigned b = __builtin_bit_cast(unsigned, f);
    b += 0x7fffu + ((b >> 16) & 1u);
    return b >> 16;
}
__device__ __forceinline__ unsigned cvtpk(float lo, float hi) {
    unsigned r;
    asm("v_cvt_pk_bf16_f32 %0, %1, %2" : "=v"(r) : "v"(lo), "v"(hi));
    return r;
}
__device__ __forceinline__ void unpack8(uint4 v, float* f) {
    f[0] = bflo(v.x); f[1] = bfhi(v.x); f[2] = bflo(v.y); f[3] = bfhi(v.y);
    f[4] = bflo(v.z); f[5] = bfhi(v.z); f[6] = bflo(v.w); f[7] = bfhi(v.w);
}

// ---------------------------------------------------------------------------
// prep: all weights -> bf16 [k][o][c] tiles.
// ---------------------------------------------------------------------------
__global__ void prep_weights(const float* __restrict__ wdef, unsigned short* __restrict__ wdefb,
                             const float* __restrict__ wdc, unsigned short* __restrict__ wdcb,
                             const float* __restrict__ woff, unsigned short* __restrict__ woffb) {
    int idx = blockIdx.x * 256 + threadIdx.x;   // grid covers 36864
    if (idx < 36864) {
        int k = idx >> 12, o = (idx >> 6) & 63, c = idx & 63;
        wdefb[idx] = (unsigned short)f2bf(wdef[(o * 64 + c) * 9 + k]);
        wdcb[idx]  = (unsigned short)f2bf(wdc[(c * 64 + o) * 9 + (8 - k)]);
    }
    if (idx < 18432) {
        int k = idx >> 11, o = (idx >> 6) & 31, c = idx & 63;
        woffb[idx] = (o < 18) ? (unsigned short)f2bf(woff[(o * 64 + c) * 9 + k])
                              : (unsigned short)0;
    }
}

// ---------------------------------------------------------------------------
// x NCHW f32 -> xb NHWC bf16 (LDS transpose, 64px x 64c tiles)
// ---------------------------------------------------------------------------
__global__ __launch_bounds__(256) void x_to_nhwc(const float* __restrict__ x,
                                                 unsigned short* __restrict__ xb) {
    __shared__ unsigned short t[64 * 72];
    int tid = threadIdx.x;
    int b = blockIdx.x >> 10;
    long pxb = (long)(blockIdx.x & 1023) * 64;
    const float* xp = x + (long)b * 64 * HW_ + pxb;
    int px = tid & 63, cg = tid >> 6;
    for (int c = cg; c < 64; c += 4)
        t[px * 72 + c] = (unsigned short)f2bf(xp[(long)c * HW_ + px]);
    __syncthreads();
    int spx = tid >> 2, q = tid & 3;
    unsigned short* dst = xb + ((long)b * HW_ + pxb + spx) * 64 + q * 16;
    *(uint4*)dst       = *(const uint4*)&t[spx * 72 + q * 16];
    *(uint4*)(dst + 8) = *(const uint4*)&t[spx * 72 + q * 16 + 8];
}

// ---------------------------------------------------------------------------
// conv1 via MFMA, double-buffered pipelined staging (r13-exact).
// xb NHWC bf16 -> h NHWC bf16 (+bias+relu). Block 128px x 64o, 4 waves.
// ---------------------------------------------------------------------------
__global__ __launch_bounds__(256, 4) void conv1_mfma(const unsigned short* __restrict__ xb,
                                                     const unsigned short* __restrict__ wdcb,
                                                     const float* __restrict__ bias,
                                                     unsigned short* __restrict__ h) {
    __shared__ __align__(16) unsigned short sA[2][130 * 72];   // 37.4KB

    int tid = threadIdx.x;
    int linear = (blockIdx.x & 7) * 128 + (blockIdx.x >> 3);   // XCD swizzle, 1024 blocks
    int bx = linear & 1;
    int y  = (linear >> 1) & 255;
    int b  = linear >> 9;
    int X0 = bx * 128;

    int wave = tid >> 6, lane = tid & 63;
    int lr = lane & 15, lg = lane >> 4;
    int n0 = wave * 16;

    f32x4 acc[8];
#pragma unroll
    for (int m = 0; m < 8; ++m) { acc[m][0]=0.f; acc[m][1]=0.f; acc[m][2]=0.f; acc[m][3]=0.f; }

    const unsigned short* xbb = xb + (long)b * HW_ * 64;
    const unsigned short* pb  = wdcb + (n0 + lr) * 64 + lg * 8;

    int r0 = (y == 0) ? 1 : 0;
    int r1 = (y == H_ - 1) ? 1 : 2;

    uint4 L[5];
    auto LOADROW = [&](int yr) {
        const unsigned short* src = xbb + (long)yr * (W_ * 64);
#pragma unroll
        for (int t = 0; t < 5; ++t) {
            int e = tid + t * 256;
            uint4 v = { 0u, 0u, 0u, 0u };
            if (e < 1040) {
                int col = X0 - 1 + (e >> 3);
                if (col >= 0 && col < W_)
                    v = *(const uint4*)&src[(long)col * 64 + (e & 7) * 8];
            }
            L[t] = v;
        }
    };

    LOADROW(y + r0 - 1);
    int pa = 0;
    for (int ky = r0; ky <= r1; ++ky, ++pa) {
        unsigned short* buf = sA[pa & 1];
#pragma unroll
        for (int t = 0; t < 5; ++t) {           // ds_write staged regs
            int e = tid + t * 256;
            if (e < 1040) *(uint4*)&buf[(e >> 3) * 72 + (e & 7) * 8] = L[t];
        }
        if (ky < r1) LOADROW(y + ky);           // next row flies over MFMA
        asm volatile("s_waitcnt lgkmcnt(0)" ::: "memory");
        __builtin_amdgcn_s_barrier();
        asm volatile("" ::: "memory");
#pragma unroll
        for (int kx = 0; kx < 3; ++kx) {
            int k = ky * 3 + kx;
            bf16x8 b0 = *(const bf16x8*)(pb + k * 4096);
            bf16x8 b1 = *(const bf16x8*)(pb + k * 4096 + 32);
#pragma unroll
            for (int m = 0; m < 8; ++m) {
                const unsigned short* ap = &buf[(m * 16 + lr + kx) * 72 + lg * 8];
                bf16x8 a0 = *(const bf16x8*)ap;
                bf16x8 a1 = *(const bf16x8*)(ap + 32);
                acc[m] = __builtin_amdgcn_mfma_f32_16x16x32_bf16(a0, b0, acc[m], 0, 0, 0);
                acc[m] = __builtin_amdgcn_mfma_f32_16x16x32_bf16(a1, b1, acc[m], 0, 0, 0);
            }
        }
    }

    // epilogue: bias+relu, repack via LDS (sA[0]) to NHWC bf16
    __syncthreads();
    float bv = bias[n0 + lr];
    unsigned short* cs = sA[0];
#pragma unroll
    for (int m = 0; m < 8; ++m)
#pragma unroll
        for (int r = 0; r < 4; ++r) {
            float vv = fmaxf(acc[m][r] + bv, 0.f);
            cs[(m * 16 + lg * 4 + r) * 72 + n0 + lr] = (unsigned short)f2bf(vv);
        }
    __syncthreads();
    int spx = tid >> 1, sc0 = (tid & 1) * 32;
    unsigned short* dst = h + ((long)b * HW_ + (long)y * W_ + X0 + spx) * 64 + sc0;
    const unsigned short* srcp = &cs[spx * 72 + sc0];
#pragma unroll
    for (int q = 0; q < 4; ++q)
        *(uint4*)(dst + q * 8) = *(const uint4*)(srcp + q * 8);
}

// ---------------------------------------------------------------------------
// conv2 via MFMA, double-buffered pipelined staging, N=18 padded to 32
// (r13-exact). h NHWC bf16 -> off NCHW f32. Block 128px x 32o, 4 waves.
// ---------------------------------------------------------------------------
__global__ __launch_bounds__(256, 4) void conv2_mfma(const unsigned short* __restrict__ h,
                                                     const unsigned short* __restrict__ woffb,
                                                     const float* __restrict__ bias,
                                                     float* __restrict__ off) {
    __shared__ __align__(16) unsigned short sA[2][130 * 72];

    int tid = threadIdx.x;
    int linear = (blockIdx.x & 7) * 128 + (blockIdx.x >> 3);   // 1024 blocks
    int bx = linear & 1;
    int y  = (linear >> 1) & 255;
    int b  = linear >> 9;
    int X0 = bx * 128;

    int wave = tid >> 6, lane = tid & 63;
    int lr = lane & 15, lg = lane >> 4;
    int pxh = wave & 1, nh = wave >> 1;
    int n0 = nh * 16;
    int pxb = pxh * 64;

    f32x4 acc[4];
#pragma unroll
    for (int m = 0; m < 4; ++m) { acc[m][0]=0.f; acc[m][1]=0.f; acc[m][2]=0.f; acc[m][3]=0.f; }

    const unsigned short* hb = h + (long)b * HW_ * 64;
    const unsigned short* pb = woffb + (n0 + lr) * 64 + lg * 8;

    int r0 = (y == 0) ? 1 : 0;
    int r1 = (y == H_ - 1) ? 1 : 2;

    uint4 L[5];
    auto LOADROW = [&](int yr) {
        const unsigned short* src = hb + (long)yr * (W_ * 64);
#pragma unroll
        for (int t = 0; t < 5; ++t) {
            int e = tid + t * 256;
            uint4 v = { 0u, 0u, 0u, 0u };
            if (e < 1040) {
                int col = X0 - 1 + (e >> 3);
                if (col >= 0 && col < W_)
                    v = *(const uint4*)&src[(long)col * 64 + (e & 7) * 8];
            }
            L[t] = v;
        }
    };

    LOADROW(y + r0 - 1);
    int pa = 0;
    for (int ky = r0; ky <= r1; ++ky, ++pa) {
        unsigned short* buf = sA[pa & 1];
#pragma unroll
        for (int t = 0; t < 5; ++t) {
            int e = tid + t * 256;
            if (e < 1040) *(uint4*)&buf[(e >> 3) * 72 + (e & 7) * 8] = L[t];
        }
        if (ky < r1) LOADROW(y + ky);
        asm volatile("s_waitcnt lgkmcnt(0)" ::: "memory");
        __builtin_amdgcn_s_barrier();
        asm volatile("" ::: "memory");
#pragma unroll
        for (int kx = 0; kx < 3; ++kx) {
            int k = ky * 3 + kx;
            bf16x8 b0 = *(const bf16x8*)(pb + k * 2048);
            bf16x8 b1 = *(const bf16x8*)(pb + k * 2048 + 32);
#pragma unroll
            for (int m = 0; m < 4; ++m) {
                const unsigned short* ap = &buf[(pxb + m * 16 + lr + kx) * 72 + lg * 8];
                bf16x8 a0 = *(const bf16x8*)ap;
                bf16x8 a1 = *(const bf16x8*)(ap + 32);
                acc[m] = __builtin_amdgcn_mfma_f32_16x16x32_bf16(a0, b0, acc[m], 0, 0, 0);
                acc[m] = __builtin_amdgcn_mfma_f32_16x16x32_bf16(a1, b1, acc[m], 0, 0, 0);
            }
        }
    }

    int o = n0 + lr;
    if (o < 18) {
        float bv = bias[o];
        float* op = off + ((long)b * 18 + o) * HW_ + (long)y * W_ + X0 + pxb;
#pragma unroll
        for (int m = 0; m < 4; ++m) {
            float4 r = { acc[m][0] + bv, acc[m][1] + bv, acc[m][2] + bv, acc[m][3] + bv };
            *(float4*)(op + m * 16 + lg * 4) = r;
        }
    }
}

// ---------------------------------------------------------------------------
// deform conv via MFMA — r16 winner EXACTLY (measured 49.7 µs): no gather
// prefetch (live set 48 VGPR), __launch_bounds__(256,5) — the verified
// allocator sweet spot (r17's (256,8) collapsed to VGPR 32 + 345MB spill;
// r12's (256,6)-on-big-liveset did the same). TLP covers exposed gather
// latency; offsets+weights prefetched; swizzled val LDS; lgkm-only barrier.
// ---------------------------------------------------------------------------
struct Pass16 {
    uint4 a00, a01, a10, a11;   // corners, chans c0..c0+8
    uint4 b00, b01, b10, b11;   // corners, chans c0+8..c0+16
    float w00, w01, w10, w11;
};

__device__ __forceinline__ Pass16 issue16(const unsigned short* __restrict__ hb,
                                          int k, int y, int px, float dy, float dx, int c0) {
    Pass16 s;
    float py  = (float)(y - 1 + k / 3) + dy;
    float pxs = (float)(px - 1 + k % 3) + dx;
    float y0f = floorf(py), x0f = floorf(pxs);
    int iy0 = (int)y0f, ix0 = (int)x0f;
    float wy1 = py - y0f, wx1 = pxs - x0f;
    float wy0 = 1.f - wy1, wx0 = 1.f - wx1;
    bool vy0 = (iy0 >= 0) && (iy0 < H_);
    bool vy1 = (iy0 >= -1) && (iy0 < H_ - 1);
    bool vx0 = (ix0 >= 0) && (ix0 < W_);
    bool vx1 = (ix0 >= -1) && (ix0 < W_ - 1);
    int cy0 = min(max(iy0, 0), H_ - 1), cy1 = min(max(iy0 + 1, 0), H_ - 1);
    int cx0 = min(max(ix0, 0), W_ - 1), cx1 = min(max(ix0 + 1, 0), W_ - 1);
    s.w00 = wy0 * wx0 * ((vy0 && vx0) ? 1.f : 0.f);
    s.w01 = wy0 * wx1 * ((vy0 && vx1) ? 1.f : 0.f);
    s.w10 = wy1 * wx0 * ((vy1 && vx0) ? 1.f : 0.f);
    s.w11 = wy1 * wx1 * ((vy1 && vx1) ? 1.f : 0.f);
    int r00 = (cy0 * W_ + cx0) * 64 + c0, r01 = (cy0 * W_ + cx1) * 64 + c0;
    int r10 = (cy1 * W_ + cx0) * 64 + c0, r11 = (cy1 * W_ + cx1) * 64 + c0;
    s.a00 = *(const uint4*)&hb[r00];     s.a01 = *(const uint4*)&hb[r01];
    s.a10 = *(const uint4*)&hb[r10];     s.a11 = *(const uint4*)&hb[r11];
    s.b00 = *(const uint4*)&hb[r00 + 8]; s.b01 = *(const uint4*)&hb[r01 + 8];
    s.b10 = *(const uint4*)&hb[r10 + 8]; s.b11 = *(const uint4*)&hb[r11 + 8];
    return s;
}

__device__ __forceinline__ uint4 interp8u(uint4 q0, uint4 q1, uint4 q2, uint4 q3,
                                          float w00, float w01, float w10, float w11) {
    float g0[8], g1[8], g2[8], g3[8];
    unpack8(q0, g0); unpack8(q1, g1); unpack8(q2, g2); unpack8(q3, g3);
    unsigned r[4];
#pragma unroll
    for (int j = 0; j < 4; ++j) {
        float lo = fmaf(g3[2*j],   w11, fmaf(g2[2*j],   w10, fmaf(g1[2*j],   w01, g0[2*j]   * w00)));
        float hi = fmaf(g3[2*j+1], w11, fmaf(g2[2*j+1], w10, fmaf(g1[2*j+1], w01, g0[2*j+1] * w00)));
        r[j] = cvtpk(lo, hi);
    }
    uint4 u = { r[0], r[1], r[2], r[3] };
    return u;
}

__global__ __launch_bounds__(256, 5) void deform_mfma(const unsigned short* __restrict__ h,
                                                      const float* __restrict__ off,
                                                      const unsigned short* __restrict__ wdefb,
                                                      const float* __restrict__ bias,
                                                      float* __restrict__ out) {
    __shared__ __align__(16) unsigned short val[2][64 * 64];   // 16KB double buffer

    int tid = threadIdx.x;
    int linear = (blockIdx.x & 7) * 256 + (blockIdx.x >> 3);   // 2048 blocks, XCD swizzle
    int b  = linear >> 10;
    int y  = (linear >> 2) & 255;
    int x0 = (linear & 3) * 64;

    int lane = tid & 63, wave = tid >> 6;
    int lr = lane & 15, lg = lane >> 4;
    int n0 = wave * 16;
    int gpx = tid >> 2;            // gather px 0..63 (channel-major: 4 lanes/pixel)
    int gc  = tid & 3;             // 16-chan chunk
    int c0  = gc * 16;
    int gx  = x0 + gpx;

    f32x4 acc[4];
#pragma unroll
    for (int m = 0; m < 4; ++m) { acc[m][0]=0.f; acc[m][1]=0.f; acc[m][2]=0.f; acc[m][3]=0.f; }

    const unsigned short* hb   = h + (long)b * HW_ * 64;
    const float* ofb  = off + (long)b * 18 * HW_ + y * W_ + gx;
    const unsigned short* bsrc = wdefb + (n0 + lr) * 64 + lg * 8;

    // prologue: tap-0 offsets
    float dyc = ofb[0], dxc = ofb[HW_];

    // swizzled LDS slots (shorts): slot index 0..7 within a 128B px row
    int slotL = ((2 * gc)     ^ (gpx & 7)) * 8;
    int slotH = ((2 * gc + 1) ^ (gpx & 7)) * 8;
    int rdL   = ((lg)     ^ (lr & 7)) * 8;
    int rdH   = ((lg + 4) ^ (lr & 7)) * 8;

    for (int k = 0; k < 9; ++k) {
        // weights for tap k + offsets for tap k+1 (issued before gathers)
        bf16x8 bc0 = *(const bf16x8*)(bsrc + k * 4096);
        bf16x8 bc1 = *(const bf16x8*)(bsrc + k * 4096 + 32);
        float dyn = 0.f, dxn = 0.f;
        if (k < 8) { dyn = ofb[(2 * k + 2) * HW_]; dxn = ofb[(2 * k + 3) * HW_]; }

        // gathers for tap k — waited immediately by interp (exposed latency,
        // covered by 5 blocks/CU TLP)
        Pass16 S = issue16(hb, k, y, gx, dyc, dxc, c0);

        unsigned short* vb = val[k & 1];
        *(uint4*)&vb[gpx * 64 + slotL] = interp8u(S.a00, S.a01, S.a10, S.a11,
                                                  S.w00, S.w01, S.w10, S.w11);
        *(uint4*)&vb[gpx * 64 + slotH] = interp8u(S.b00, S.b01, S.b10, S.b11,
                                                  S.w00, S.w01, S.w10, S.w11);

        asm volatile("s_waitcnt lgkmcnt(0)" ::: "memory");  // my ds_writes committed
        __builtin_amdgcn_s_barrier();                       // vmcnt NOT drained
        asm volatile("" ::: "memory");                      // keep ds_reads below barrier

        __builtin_amdgcn_s_setprio(1);
#pragma unroll
        for (int m = 0; m < 4; ++m) {
            const unsigned short* ap = &vb[(m * 16 + lr) * 64];
            bf16x8 a0 = *(const bf16x8*)&ap[rdL];
            bf16x8 a1 = *(const bf16x8*)&ap[rdH];
            acc[m] = __builtin_amdgcn_mfma_f32_16x16x32_bf16(a0, bc0, acc[m], 0, 0, 0);
            acc[m] = __builtin_amdgcn_mfma_f32_16x16x32_bf16(a1, bc1, acc[m], 0, 0, 0);
        }
        __builtin_amdgcn_s_setprio(0);

        dyc = dyn; dxc = dxn;
    }

    // epilogue: D col=lane&15 -> o = n0+lr; row -> px = m*16+lg*4+r
    float bv = bias[n0 + lr];
    float* outb = out + ((long)b * 64 + n0 + lr) * HW_ + y * W_ + x0;
#pragma unroll
    for (int m = 0; m < 4; ++m) {
        float4 r = { fmaxf(acc[m][0] + bv, 0.f), fmaxf(acc[m][1] + bv, 0.f),
                     fmaxf(acc[m][2] + bv, 0.f), fmaxf(acc[m][3] + bv, 0.f) };
        *(float4*)(outb + m * 16 + lg * 4) = r;
    }
}

// ---------------------------------------------------------------------------
extern "C" void kernel_launch(void* const* d_in, const int* in_sizes, int n_in,
                              void* d_out, int out_size, void* d_ws, size_t ws_size,
                              hipStream_t stream) {
    const float* x        = (const float*)d_in[0];
    const float* w_deconv = (const float*)d_in[1];
    const float* b_deconv = (const float*)d_in[2];
    const float* w_off    = (const float*)d_in[3];
    const float* b_off    = (const float*)d_in[4];
    const float* w_def    = (const float*)d_in[5];
    const float* b_def    = (const float*)d_in[6];
    float* out = (float*)d_out;

    char* ws = (char*)d_ws;
    unsigned short* xbb   = (unsigned short*)ws;               // 16,777,216 B
    unsigned short* hbf   = (unsigned short*)(ws + 16777216);  // 16,777,216 B
    float* offset         = (float*)(ws + 33554432);           //  9,437,184 B
    unsigned short* wdcb  = (unsigned short*)(ws + 42991616);  //     73,728 B
    unsigned short* wdefb = (unsigned short*)(ws + 43065344);  //     73,728 B
    unsigned short* woffb = (unsigned short*)(ws + 43139072);  //     36,864 B

    prep_weights<<<144, 256, 0, stream>>>(w_def, wdefb, w_deconv, wdcb, w_off, woffb);
    x_to_nhwc<<<2048, 256, 0, stream>>>(x, xbb);
    conv1_mfma<<<1024, 256, 0, stream>>>(xbb, wdcb, b_deconv, hbf);
    conv2_mfma<<<1024, 256, 0, stream>>>(hbf, woffb, b_off, offset);
    deform_mfma<<<2048, 256, 0, stream>>>(hbf, offset, wdefb, b_def, out);
}

// Round 19
// 95.178 us; speedup vs baseline: 2.0926x; 1.0214x over previous
//
#include <hip/hip_runtime.h>

#define H_ 256
#define W_ 256
#define HW_ (H_*W_)

typedef __attribute__((ext_vector_type(8))) short bf16x8;
typedef __attribute__((ext_vector_type(4))) float f32x4;

// ---- bf16 helpers ----------------------------------------------------------
__device__ __forceinline__ float bflo(unsigned u) { return __builtin_bit_cast(float, u << 16); }
__device__ __forceinline__ float bfhi(unsigned u) { return __builtin_bit_cast(float, u & 0xffff0000u); }
__device__ __forceinline__ unsigned f2bf(float f) {
    unsigned b = __builtin_bit_cast(unsigned, f);
    b += 0x7fffu + ((b >> 16) & 1u);
    return b >> 16;
}
__device__ __forceinline__ unsigned cvtpk(float lo, float hi) {
    unsigned r;
    asm("v_cvt_pk_bf16_f32 %0, %1, %2" : "=v"(r) : "v"(lo), "v"(hi));
    return r;
}
__device__ __forceinline__ void unpack8(uint4 v, float* f) {
    f[0] = bflo(v.x); f[1] = bfhi(v.x); f[2] = bflo(v.y); f[3] = bfhi(v.y);
    f[4] = bflo(v.z); f[5] = bfhi(v.z); f[6] = bflo(v.w); f[7] = bfhi(v.w);
}

// ---------------------------------------------------------------------------
// prep: all weights -> bf16 [k][o][c] tiles.
// ---------------------------------------------------------------------------
__global__ void prep_weights(const float* __restrict__ wdef, unsigned short* __restrict__ wdefb,
                             const float* __restrict__ wdc, unsigned short* __restrict__ wdcb,
                             const float* __restrict__ woff, unsigned short* __restrict__ woffb) {
    int idx = blockIdx.x * 256 + threadIdx.x;   // grid covers 36864
    if (idx < 36864) {
        int k = idx >> 12, o = (idx >> 6) & 63, c = idx & 63;
        wdefb[idx] = (unsigned short)f2bf(wdef[(o * 64 + c) * 9 + k]);
        wdcb[idx]  = (unsigned short)f2bf(wdc[(c * 64 + o) * 9 + (8 - k)]);
    }
    if (idx < 18432) {
        int k = idx >> 11, o = (idx >> 6) & 31, c = idx & 63;
        woffb[idx] = (o < 18) ? (unsigned short)f2bf(woff[(o * 64 + c) * 9 + k])
                              : (unsigned short)0;
    }
}

// ---------------------------------------------------------------------------
// x NCHW f32 -> xb NHWC bf16 (LDS transpose, 64px x 64c tiles)
// ---------------------------------------------------------------------------
__global__ __launch_bounds__(256) void x_to_nhwc(const float* __restrict__ x,
                                                 unsigned short* __restrict__ xb) {
    __shared__ unsigned short t[64 * 72];
    int tid = threadIdx.x;
    int b = blockIdx.x >> 10;
    long pxb = (long)(blockIdx.x & 1023) * 64;
    const float* xp = x + (long)b * 64 * HW_ + pxb;
    int px = tid & 63, cg = tid >> 6;
    for (int c = cg; c < 64; c += 4)
        t[px * 72 + c] = (unsigned short)f2bf(xp[(long)c * HW_ + px]);
    __syncthreads();
    int spx = tid >> 2, q = tid & 3;
    unsigned short* dst = xb + ((long)b * HW_ + pxb + spx) * 64 + q * 16;
    *(uint4*)dst       = *(const uint4*)&t[spx * 72 + q * 16];
    *(uint4*)(dst + 8) = *(const uint4*)&t[spx * 72 + q * 16 + 8];
}

// ---------------------------------------------------------------------------
// conv1 via MFMA, double-buffered pipelined staging (r13-exact).
// xb NHWC bf16 -> h NHWC bf16 (+bias+relu). Block 128px x 64o, 4 waves.
// ---------------------------------------------------------------------------
__global__ __launch_bounds__(256, 4) void conv1_mfma(const unsigned short* __restrict__ xb,
                                                     const unsigned short* __restrict__ wdcb,
                                                     const float* __restrict__ bias,
                                                     unsigned short* __restrict__ h) {
    __shared__ __align__(16) unsigned short sA[2][130 * 72];   // 37.4KB

    int tid = threadIdx.x;
    int linear = (blockIdx.x & 7) * 128 + (blockIdx.x >> 3);   // XCD swizzle, 1024 blocks
    int bx = linear & 1;
    int y  = (linear >> 1) & 255;
    int b  = linear >> 9;
    int X0 = bx * 128;

    int wave = tid >> 6, lane = tid & 63;
    int lr = lane & 15, lg = lane >> 4;
    int n0 = wave * 16;

    f32x4 acc[8];
#pragma unroll
    for (int m = 0; m < 8; ++m) { acc[m][0]=0.f; acc[m][1]=0.f; acc[m][2]=0.f; acc[m][3]=0.f; }

    const unsigned short* xbb = xb + (long)b * HW_ * 64;
    const unsigned short* pb  = wdcb + (n0 + lr) * 64 + lg * 8;

    int r0 = (y == 0) ? 1 : 0;
    int r1 = (y == H_ - 1) ? 1 : 2;

    uint4 L[5];
    auto LOADROW = [&](int yr) {
        const unsigned short* src = xbb + (long)yr * (W_ * 64);
#pragma unroll
        for (int t = 0; t < 5; ++t) {
            int e = tid + t * 256;
            uint4 v = { 0u, 0u, 0u, 0u };
            if (e < 1040) {
                int col = X0 - 1 + (e >> 3);
                if (col >= 0 && col < W_)
                    v = *(const uint4*)&src[(long)col * 64 + (e & 7) * 8];
            }
            L[t] = v;
        }
    };

    LOADROW(y + r0 - 1);
    int pa = 0;
    for (int ky = r0; ky <= r1; ++ky, ++pa) {
        unsigned short* buf = sA[pa & 1];
#pragma unroll
        for (int t = 0; t < 5; ++t) {           // ds_write staged regs
            int e = tid + t * 256;
            if (e < 1040) *(uint4*)&buf[(e >> 3) * 72 + (e & 7) * 8] = L[t];
        }
        if (ky < r1) LOADROW(y + ky);           // next row flies over MFMA
        asm volatile("s_waitcnt lgkmcnt(0)" ::: "memory");
        __builtin_amdgcn_s_barrier();
        asm volatile("" ::: "memory");
#pragma unroll
        for (int kx = 0; kx < 3; ++kx) {
            int k = ky * 3 + kx;
            bf16x8 b0 = *(const bf16x8*)(pb + k * 4096);
            bf16x8 b1 = *(const bf16x8*)(pb + k * 4096 + 32);
#pragma unroll
            for (int m = 0; m < 8; ++m) {
                const unsigned short* ap = &buf[(m * 16 + lr + kx) * 72 + lg * 8];
                bf16x8 a0 = *(const bf16x8*)ap;
                bf16x8 a1 = *(const bf16x8*)(ap + 32);
                acc[m] = __builtin_amdgcn_mfma_f32_16x16x32_bf16(a0, b0, acc[m], 0, 0, 0);
                acc[m] = __builtin_amdgcn_mfma_f32_16x16x32_bf16(a1, b1, acc[m], 0, 0, 0);
            }
        }
    }

    // epilogue: bias+relu, repack via LDS (sA[0]) to NHWC bf16
    __syncthreads();
    float bv = bias[n0 + lr];
    unsigned short* cs = sA[0];
#pragma unroll
    for (int m = 0; m < 8; ++m)
#pragma unroll
        for (int r = 0; r < 4; ++r) {
            float vv = fmaxf(acc[m][r] + bv, 0.f);
            cs[(m * 16 + lg * 4 + r) * 72 + n0 + lr] = (unsigned short)f2bf(vv);
        }
    __syncthreads();
    int spx = tid >> 1, sc0 = (tid & 1) * 32;
    unsigned short* dst = h + ((long)b * HW_ + (long)y * W_ + X0 + spx) * 64 + sc0;
    const unsigned short* srcp = &cs[spx * 72 + sc0];
#pragma unroll
    for (int q = 0; q < 4; ++q)
        *(uint4*)(dst + q * 8) = *(const uint4*)(srcp + q * 8);
}

// ---------------------------------------------------------------------------
// conv2 via MFMA, double-buffered pipelined staging, N=18 padded to 32
// (r13-exact). h NHWC bf16 -> off NCHW f32. Block 128px x 32o, 4 waves.
// ---------------------------------------------------------------------------
__global__ __launch_bounds__(256, 4) void conv2_mfma(const unsigned short* __restrict__ h,
                                                     const unsigned short* __restrict__ woffb,
                                                     const float* __restrict__ bias,
                                                     float* __restrict__ off) {
    __shared__ __align__(16) unsigned short sA[2][130 * 72];

    int tid = threadIdx.x;
    int linear = (blockIdx.x & 7) * 128 + (blockIdx.x >> 3);   // 1024 blocks
    int bx = linear & 1;
    int y  = (linear >> 1) & 255;
    int b  = linear >> 9;
    int X0 = bx * 128;

    int wave = tid >> 6, lane = tid & 63;
    int lr = lane & 15, lg = lane >> 4;
    int pxh = wave & 1, nh = wave >> 1;
    int n0 = nh * 16;
    int pxb = pxh * 64;

    f32x4 acc[4];
#pragma unroll
    for (int m = 0; m < 4; ++m) { acc[m][0]=0.f; acc[m][1]=0.f; acc[m][2]=0.f; acc[m][3]=0.f; }

    const unsigned short* hb = h + (long)b * HW_ * 64;
    const unsigned short* pb = woffb + (n0 + lr) * 64 + lg * 8;

    int r0 = (y == 0) ? 1 : 0;
    int r1 = (y == H_ - 1) ? 1 : 2;

    uint4 L[5];
    auto LOADROW = [&](int yr) {
        const unsigned short* src = hb + (long)yr * (W_ * 64);
#pragma unroll
        for (int t = 0; t < 5; ++t) {
            int e = tid + t * 256;
            uint4 v = { 0u, 0u, 0u, 0u };
            if (e < 1040) {
                int col = X0 - 1 + (e >> 3);
                if (col >= 0 && col < W_)
                    v = *(const uint4*)&src[(long)col * 64 + (e & 7) * 8];
            }
            L[t] = v;
        }
    };

    LOADROW(y + r0 - 1);
    int pa = 0;
    for (int ky = r0; ky <= r1; ++ky, ++pa) {
        unsigned short* buf = sA[pa & 1];
#pragma unroll
        for (int t = 0; t < 5; ++t) {
            int e = tid + t * 256;
            if (e < 1040) *(uint4*)&buf[(e >> 3) * 72 + (e & 7) * 8] = L[t];
        }
        if (ky < r1) LOADROW(y + ky);
        asm volatile("s_waitcnt lgkmcnt(0)" ::: "memory");
        __builtin_amdgcn_s_barrier();
        asm volatile("" ::: "memory");
#pragma unroll
        for (int kx = 0; kx < 3; ++kx) {
            int k = ky * 3 + kx;
            bf16x8 b0 = *(const bf16x8*)(pb + k * 2048);
            bf16x8 b1 = *(const bf16x8*)(pb + k * 2048 + 32);
#pragma unroll
            for (int m = 0; m < 4; ++m) {
                const unsigned short* ap = &buf[(pxb + m * 16 + lr + kx) * 72 + lg * 8];
                bf16x8 a0 = *(const bf16x8*)ap;
                bf16x8 a1 = *(const bf16x8*)(ap + 32);
                acc[m] = __builtin_amdgcn_mfma_f32_16x16x32_bf16(a0, b0, acc[m], 0, 0, 0);
                acc[m] = __builtin_amdgcn_mfma_f32_16x16x32_bf16(a1, b1, acc[m], 0, 0, 0);
            }
        }
    }

    int o = n0 + lr;
    if (o < 18) {
        float bv = bias[o];
        float* op = off + ((long)b * 18 + o) * HW_ + (long)y * W_ + X0 + pxb;
#pragma unroll
        for (int m = 0; m < 4; ++m) {
            float4 r = { acc[m][0] + bv, acc[m][1] + bv, acc[m][2] + bv, acc[m][3] + bv };
            *(float4*)(op + m * 16 + lg * 4) = r;
        }
    }
}

// ---------------------------------------------------------------------------
// deform conv via MFMA — half-step gather prefetch: gathers for tap k+1 are
// issued AFTER the barrier, immediately before MFMA(k); regs live only across
// the MFMA phase (~80-90 live total, cap 102 at (256,5)). Weight loads for
// tap k are issued at loop-top (OLDEST VMEM) so the MFMA's implicit vmcnt
// drains only weights, never the in-flight gathers. sched_barrier(0) pins
// the gather issue above the MFMA cluster. Swizzled val LDS; lgkm-only
// barrier per tap (r16 base, measured 49.7 µs).
// ---------------------------------------------------------------------------
struct Pass16 {
    uint4 a00, a01, a10, a11;   // corners, chans c0..c0+8
    uint4 b00, b01, b10, b11;   // corners, chans c0+8..c0+16
    float w00, w01, w10, w11;
};

__device__ __forceinline__ Pass16 issue16(const unsigned short* __restrict__ hb,
                                          int k, int y, int px, float dy, float dx, int c0) {
    Pass16 s;
    float py  = (float)(y - 1 + k / 3) + dy;
    float pxs = (float)(px - 1 + k % 3) + dx;
    float y0f = floorf(py), x0f = floorf(pxs);
    int iy0 = (int)y0f, ix0 = (int)x0f;
    float wy1 = py - y0f, wx1 = pxs - x0f;
    float wy0 = 1.f - wy1, wx0 = 1.f - wx1;
    bool vy0 = (iy0 >= 0) && (iy0 < H_);
    bool vy1 = (iy0 >= -1) && (iy0 < H_ - 1);
    bool vx0 = (ix0 >= 0) && (ix0 < W_);
    bool vx1 = (ix0 >= -1) && (ix0 < W_ - 1);
    int cy0 = min(max(iy0, 0), H_ - 1), cy1 = min(max(iy0 + 1, 0), H_ - 1);
    int cx0 = min(max(ix0, 0), W_ - 1), cx1 = min(max(ix0 + 1, 0), W_ - 1);
    s.w00 = wy0 * wx0 * ((vy0 && vx0) ? 1.f : 0.f);
    s.w01 = wy0 * wx1 * ((vy0 && vx1) ? 1.f : 0.f);
    s.w10 = wy1 * wx0 * ((vy1 && vx0) ? 1.f : 0.f);
    s.w11 = wy1 * wx1 * ((vy1 && vx1) ? 1.f : 0.f);
    int r00 = (cy0 * W_ + cx0) * 64 + c0, r01 = (cy0 * W_ + cx1) * 64 + c0;
    int r10 = (cy1 * W_ + cx0) * 64 + c0, r11 = (cy1 * W_ + cx1) * 64 + c0;
    s.a00 = *(const uint4*)&hb[r00];     s.a01 = *(const uint4*)&hb[r01];
    s.a10 = *(const uint4*)&hb[r10];     s.a11 = *(const uint4*)&hb[r11];
    s.b00 = *(const uint4*)&hb[r00 + 8]; s.b01 = *(const uint4*)&hb[r01 + 8];
    s.b10 = *(const uint4*)&hb[r10 + 8]; s.b11 = *(const uint4*)&hb[r11 + 8];
    return s;
}

__device__ __forceinline__ uint4 interp8u(uint4 q0, uint4 q1, uint4 q2, uint4 q3,
                                          float w00, float w01, float w10, float w11) {
    float g0[8], g1[8], g2[8], g3[8];
    unpack8(q0, g0); unpack8(q1, g1); unpack8(q2, g2); unpack8(q3, g3);
    unsigned r[4];
#pragma unroll
    for (int j = 0; j < 4; ++j) {
        float lo = fmaf(g3[2*j],   w11, fmaf(g2[2*j],   w10, fmaf(g1[2*j],   w01, g0[2*j]   * w00)));
        float hi = fmaf(g3[2*j+1], w11, fmaf(g2[2*j+1], w10, fmaf(g1[2*j+1], w01, g0[2*j+1] * w00)));
        r[j] = cvtpk(lo, hi);
    }
    uint4 u = { r[0], r[1], r[2], r[3] };
    return u;
}

__global__ __launch_bounds__(256, 5) void deform_mfma(const unsigned short* __restrict__ h,
                                                      const float* __restrict__ off,
                                                      const unsigned short* __restrict__ wdefb,
                                                      const float* __restrict__ bias,
                                                      float* __restrict__ out) {
    __shared__ __align__(16) unsigned short val[2][64 * 64];   // 16KB double buffer

    int tid = threadIdx.x;
    int linear = (blockIdx.x & 7) * 256 + (blockIdx.x >> 3);   // 2048 blocks, XCD swizzle
    int b  = linear >> 10;
    int y  = (linear >> 2) & 255;
    int x0 = (linear & 3) * 64;

    int lane = tid & 63, wave = tid >> 6;
    int lr = lane & 15, lg = lane >> 4;
    int n0 = wave * 16;
    int gpx = tid >> 2;            // gather px 0..63 (channel-major: 4 lanes/pixel)
    int gc  = tid & 3;             // 16-chan chunk
    int c0  = gc * 16;
    int gx  = x0 + gpx;

    f32x4 acc[4];
#pragma unroll
    for (int m = 0; m < 4; ++m) { acc[m][0]=0.f; acc[m][1]=0.f; acc[m][2]=0.f; acc[m][3]=0.f; }

    const unsigned short* hb   = h + (long)b * HW_ * 64;
    const float* ofb  = off + (long)b * 18 * HW_ + y * W_ + gx;
    const unsigned short* bsrc = wdefb + (n0 + lr) * 64 + lg * 8;

    // prologue: tap-0 offsets + gathers; tap-1 offsets
    float dy0 = ofb[0], dx0 = ofb[HW_];
    Pass16 S = issue16(hb, 0, y, gx, dy0, dx0, c0);
    float dyn = ofb[2 * HW_], dxn = ofb[3 * HW_];

    // swizzled LDS slots (shorts): slot index 0..7 within a 128B px row
    int slotL = ((2 * gc)     ^ (gpx & 7)) * 8;
    int slotH = ((2 * gc + 1) ^ (gpx & 7)) * 8;
    int rdL   = ((lg)     ^ (lr & 7)) * 8;
    int rdH   = ((lg + 4) ^ (lr & 7)) * 8;

    for (int k = 0; k < 9; ++k) {
        // weights for tap k — issued FIRST (oldest VMEM this iteration), so the
        // MFMA's implicit vmcnt wait never drains the gathers issued below.
        bf16x8 bc0 = *(const bf16x8*)(bsrc + k * 4096);
        bf16x8 bc1 = *(const bf16x8*)(bsrc + k * 4096 + 32);

        // interp tap k (S's gathers: issued last iteration before MFMA(k-1),
        // latency partially hidden under that MFMA + this iteration's setup)
        unsigned short* vb = val[k & 1];
        *(uint4*)&vb[gpx * 64 + slotL] = interp8u(S.a00, S.a01, S.a10, S.a11,
                                                  S.w00, S.w01, S.w10, S.w11);
        *(uint4*)&vb[gpx * 64 + slotH] = interp8u(S.b00, S.b01, S.b10, S.b11,
                                                  S.w00, S.w01, S.w10, S.w11);

        asm volatile("s_waitcnt lgkmcnt(0)" ::: "memory");  // my ds_writes committed
        __builtin_amdgcn_s_barrier();                       // vmcnt NOT drained
        asm volatile("" ::: "memory");                      // keep ds_reads below barrier

        // issue gathers for tap k+1 + offsets for tap k+2 — held only across
        // the MFMA phase below, consumed by next iteration's interp.
        Pass16 S2;
        float dy3 = 0.f, dx3 = 0.f;
        if (k < 8) {
            S2 = issue16(hb, k + 1, y, gx, dyn, dxn, c0);
            if (k < 7) { dy3 = ofb[(2 * k + 4) * HW_]; dx3 = ofb[(2 * k + 5) * HW_]; }
        }
        __builtin_amdgcn_sched_barrier(0);                  // pin gather issue above MFMA

        __builtin_amdgcn_s_setprio(1);
#pragma unroll
        for (int m = 0; m < 4; ++m) {
            const unsigned short* ap = &vb[(m * 16 + lr) * 64];
            bf16x8 a0 = *(const bf16x8*)&ap[rdL];
            bf16x8 a1 = *(const bf16x8*)&ap[rdH];
            acc[m] = __builtin_amdgcn_mfma_f32_16x16x32_bf16(a0, bc0, acc[m], 0, 0, 0);
            acc[m] = __builtin_amdgcn_mfma_f32_16x16x32_bf16(a1, bc1, acc[m], 0, 0, 0);
        }
        __builtin_amdgcn_s_setprio(0);

        S = S2; dyn = dy3; dxn = dx3;
    }

    // epilogue: D col=lane&15 -> o = n0+lr; row -> px = m*16+lg*4+r
    float bv = bias[n0 + lr];
    float* outb = out + ((long)b * 64 + n0 + lr) * HW_ + y * W_ + x0;
#pragma unroll
    for (int m = 0; m < 4; ++m) {
        float4 r = { fmaxf(acc[m][0] + bv, 0.f), fmaxf(acc[m][1] + bv, 0.f),
                     fmaxf(acc[m][2] + bv, 0.f), fmaxf(acc[m][3] + bv, 0.f) };
        *(float4*)(outb + m * 16 + lg * 4) = r;
    }
}

// ---------------------------------------------------------------------------
extern "C" void kernel_launch(void* const* d_in, const int* in_sizes, int n_in,
                              void* d_out, int out_size, void* d_ws, size_t ws_size,
                              hipStream_t stream) {
    const float* x        = (const float*)d_in[0];
    const float* w_deconv = (const float*)d_in[1];
    const float* b_deconv = (const float*)d_in[2];
    const float* w_off    = (const float*)d_in[3];
    const float* b_off    = (const float*)d_in[4];
    const float* w_def    = (const float*)d_in[5];
    const float* b_def    = (const float*)d_in[6];
    float* out = (float*)d_out;

    char* ws = (char*)d_ws;
    unsigned short* xbb   = (unsigned short*)ws;               // 16,777,216 B
    unsigned short* hbf   = (unsigned short*)(ws + 16777216);  // 16,777,216 B
    float* offset         = (float*)(ws + 33554432);           //  9,437,184 B
    unsigned short* wdcb  = (unsigned short*)(ws + 42991616);  //     73,728 B
    unsigned short* wdefb = (unsigned short*)(ws + 43065344);  //     73,728 B
    unsigned short* woffb = (unsigned short*)(ws + 43139072);  //     36,864 B

    prep_weights<<<144, 256, 0, stream>>>(w_def, wdefb, w_deconv, wdcb, w_off, woffb);
    x_to_nhwc<<<2048, 256, 0, stream>>>(x, xbb);
    conv1_mfma<<<1024, 256, 0, stream>>>(xbb, wdcb, b_deconv, hbf);
    conv2_mfma<<<1024, 256, 0, stream>>>(hbf, woffb, b_off, offset);
    deform_mfma<<<2048, 256, 0, stream>>>(hbf, offset, wdefb, b_def, out);
}